// Round 10
// baseline (149.362 us; speedup 1.0000x reference)
//
#include <hip/hip_runtime.h>

#define N_NODES 8192
#define IN_F    1024
#define OUT_F   512
#define N_EDGES 262144
#define STRIDE  96                // fixed adjacency row stride; P(deg>=96) ~ 1e-18

// ---------------- workspace layout (bytes) ----------------
#define HID_OFF     0u            // 8192*512*2   =  8,388,608  (bf16 H)
#define XB_OFF      8388608u      // 8192*1024*2  = 16,777,216  (bf16 X)
#define WB_OFF      25165824u     // 512*1024*2   =  1,048,576  (bf16 W, contiguous after Xb)
#define DEG_OFF     26214400u     // 8192*4 = 32,768
#define COL_OFF     26247168u     // 8192*96*4 = 3,145,728
#define UCNT_OFF    29392896u     // 8192*4 = 32,768
#define UCOL_OFF    29425664u     // 8192*96*4 = 3,145,728 -> ends 32,571,392
#define MAX_DEG     STRIDE

typedef short  bf16x8 __attribute__((ext_vector_type(8)));
typedef float  f32x4  __attribute__((ext_vector_type(4)));
typedef float  f32x2  __attribute__((ext_vector_type(2)));

__device__ __forceinline__ unsigned short f2bf(float f) {
    unsigned u = __float_as_uint(f);
    u += 0x7fffu + ((u >> 16) & 1u);   // round-to-nearest-even
    return (unsigned short)(u >> 16);
}

__device__ __forceinline__ float bflo(unsigned u) { return __uint_as_float(u << 16); }
__device__ __forceinline__ float bfhi(unsigned u) { return __uint_as_float(u & 0xffff0000u); }

__device__ __forceinline__ void ld_lds16(const void* g, void* l) {
    __builtin_amdgcn_global_load_lds(
        (const __attribute__((address_space(1))) void*)g,
        (__attribute__((address_space(3))) void*)l, 16, 0, 0);
}

// --- fused: edge scatter (blocks 0..1023) + fp32->bf16 cvt (1024..5375) ---
// scatter (latency-bound) overlaps the BW-bound cvt.  deg[] zeroed by a
// stream-ordered hipMemsetAsync before this kernel (no race).
#define NX8 (N_NODES * IN_F / 8)          // 1,048,576 chunks of 8
#define NW8 (OUT_F * IN_F / 8)            //    65,536  (NX8+NW8 = 4352*256 exactly)
#define SCAT_BLOCKS 1024
__global__ __launch_bounds__(256) void cvt_scatter(const float* __restrict__ x,
                                                   const float* __restrict__ w,
                                                   unsigned short* __restrict__ xb,
                                                   const int* __restrict__ src,
                                                   const int* __restrict__ dst,
                                                   int* __restrict__ deg,
                                                   int* __restrict__ col) {
    const int bid = blockIdx.x;
    if (bid < SCAT_BLOCKS) {              // ---- scatter part ----
        int e = bid * 256 + threadIdx.x;  // 1024*256 == N_EDGES exactly
        int s = src[e];
        int slot = atomicAdd(&deg[s], 1);
        if (slot < STRIDE) col[s * STRIDE + slot] = dst[e];
        return;
    }
    int i = (bid - SCAT_BLOCKS) * 256 + threadIdx.x;
    if (i >= NX8 + NW8) return;
    const f32x4* p = (i < NX8) ? ((const f32x4*)x + (size_t)i * 2)
                               : ((const f32x4*)w + (size_t)(i - NX8) * 2);
    f32x4 v0 = __builtin_nontemporal_load(p);      // x/w never re-read as fp32
    f32x4 v1 = __builtin_nontemporal_load(p + 1);
    uint4 o;
    o.x = (unsigned)f2bf(v0.x) | ((unsigned)f2bf(v0.y) << 16);
    o.y = (unsigned)f2bf(v0.z) | ((unsigned)f2bf(v0.w) << 16);
    o.z = (unsigned)f2bf(v1.x) | ((unsigned)f2bf(v1.y) << 16);
    o.w = (unsigned)f2bf(v1.z) | ((unsigned)f2bf(v1.w) << 16);
    *((uint4*)xb + i) = o;
}

// ------- fused: MFMA GEMM (blocks 0..255) + dedup (256..2303) -------------
// R9 counters proved the GEMM is STAGED-BYTES-bound: time = staged/(7.4 TB/s)
// (196 MB -> 26.3us bf16; 320 MB -> 43.7us fp32; exact linear).  So: 128x128
// tile -> staged = A x4 + B x64 = 64+64 = 128 MB (-35%).  A-sharing blocks
// {m, m+64, m+128, m+192} land on ONE XCD (64%8==0) and the per-XCD working
// set (2 MB X-rows + 1 MB W) fits the 4 MB L2 -> A re-fetches are L2 hits.
// 4 waves (2m x 2n), wave = 64x64 out (4x4 frags).  Simple dbuf, 1 barrier
// per K-step (schedule edits proven neutral: R1/R8).  Same XOR swizzle.
// Dedup rides in this kernel: its input (deg/col from k1's scatter) is
// complete at the kernel boundary; dedup blocks fill the 2nd block-slot/CU.
#define GEMM_BLOCKS 256

__global__ __launch_bounds__(256, 2) void gemm_dedup(const unsigned short* __restrict__ Xb,
                                                     const unsigned short* __restrict__ Wb,
                                                     const float* __restrict__ bias,
                                                     unsigned short* __restrict__ H,
                                                     const int* __restrict__ dg,
                                                     const int* __restrict__ col,
                                                     int* __restrict__ ucol,
                                                     int* __restrict__ ucnt) {
    __shared__ unsigned short As[2][128 * 64];   // 32 KB
    __shared__ unsigned short Bs[2][128 * 64];   // 32 KB -> 64 KB total, 2 blk/CU
    __shared__ int wcnt[4];

    const int bid = blockIdx.x;
    const int tid = threadIdx.x;
    const int lane = tid & 63;
    const int wave = tid >> 6;

    if (bid >= GEMM_BLOCKS) {                 // ---- dedup part ----
        int* nbr = (int*)&As[0][0];           // alias gemm LDS: [4][MAX_DEG]
        int* mynbr = nbr + wave * MAX_DEG;
        const int v = (bid - GEMM_BLOCKS) * 4 + wave;
        int d = dg[v];
        if (d > MAX_DEG) d = MAX_DEG;

        if (lane == 0) wcnt[wave] = 0;
        int id0 = -1, id1 = -1;
        if (lane < d)      { id0 = col[v * STRIDE + lane];      mynbr[lane]      = id0; }
        if (64 + lane < d) { id1 = col[v * STRIDE + 64 + lane]; mynbr[64 + lane] = id1; }
        __builtin_amdgcn_wave_barrier();      // wave-synchronous LDS hand-off

        bool k0 = (lane < d);
        const int lim0 = k0 ? lane : 0;
        for (int j = 0; j < lim0; ++j) k0 = k0 & (mynbr[j] != id0);
        bool k1 = (64 + lane < d);
        const int lim1 = k1 ? (64 + lane) : 0;
        for (int j = 0; j < lim1; ++j) k1 = k1 & (mynbr[j] != id1);
        if (k0) ucol[v * STRIDE + atomicAdd(&wcnt[wave], 1)] = id0;
        if (k1) ucol[v * STRIDE + atomicAdd(&wcnt[wave], 1)] = id1;
        __builtin_amdgcn_wave_barrier();
        if (lane == 0) ucnt[v] = wcnt[wave];
        return;
    }

    // ---- GEMM part: 128x128 tile ----
    const int row0 = (bid & 63) * 128;        // 64 M-tiles; m%8 == bid%8 -> XCD-local A
    const int col0 = (bid >> 6) * 128;        // 4 N-tiles
    const int wm   = (wave & 1) * 64;
    const int wn   = (wave >> 1) * 64;
    const int fm   = lane & 15;
    const int fm7  = fm & 7;
    const int q    = lane >> 4;               // k-quad within the 32-k MFMA window

    f32x4 acc[4][4];
#pragma unroll
    for (int i = 0; i < 4; ++i)
#pragma unroll
        for (int j = 0; j < 4; ++j) acc[i][j] = (f32x4)0.f;

    // staging: slot = tid covers (r = tid>>3, swizzled k-chunk); +256 -> r+32, ...
    const int r0 = tid >> 3;                              // 0..31
    const int kp = ((tid & 7) ^ (r0 & 7)) * 8;            // swizzled k elem-offset
    const unsigned short* Xbase = Xb + (size_t)(row0 + r0) * IN_F + kp;
    const unsigned short* Wbase = Wb + (size_t)(col0 + r0) * IN_F + kp;

#define STAGE(buf, k0s) do {                                                  \
    ld_lds16(Xbase            + (k0s), &As[buf][tid * 8]);                    \
    ld_lds16(Xbase + 32*IN_F  + (k0s), &As[buf][(tid + 256) * 8]);            \
    ld_lds16(Xbase + 64*IN_F  + (k0s), &As[buf][(tid + 512) * 8]);            \
    ld_lds16(Xbase + 96*IN_F  + (k0s), &As[buf][(tid + 768) * 8]);            \
    ld_lds16(Wbase            + (k0s), &Bs[buf][tid * 8]);                    \
    ld_lds16(Wbase + 32*IN_F  + (k0s), &Bs[buf][(tid + 256) * 8]);            \
    ld_lds16(Wbase + 64*IN_F  + (k0s), &Bs[buf][(tid + 512) * 8]);            \
    ld_lds16(Wbase + 96*IN_F  + (k0s), &Bs[buf][(tid + 768) * 8]);            \
} while (0)

#define COMPUTE(buf) do {                                                     \
    _Pragma("unroll")                                                         \
    for (int s2 = 0; s2 < 2; ++s2) {                                          \
        const int kq = s2 * 4 + q;                                            \
        bf16x8 a[4], b[4];                                                    \
        _Pragma("unroll")                                                     \
        for (int mi = 0; mi < 4; ++mi)                                        \
            a[mi] = *(const bf16x8*)&As[buf][(((wm + mi*16 + fm) << 3) + (kq ^ fm7)) << 3]; \
        _Pragma("unroll")                                                     \
        for (int ni = 0; ni < 4; ++ni)                                        \
            b[ni] = *(const bf16x8*)&Bs[buf][(((wn + ni*16 + fm) << 3) + (kq ^ fm7)) << 3]; \
        _Pragma("unroll")                                                     \
        for (int mi = 0; mi < 4; ++mi)                                        \
            _Pragma("unroll")                                                 \
            for (int ni = 0; ni < 4; ++ni)                                    \
                acc[mi][ni] = __builtin_amdgcn_mfma_f32_16x16x32_bf16(        \
                    a[mi], b[ni], acc[mi][ni], 0, 0, 0);                      \
    }                                                                         \
} while (0)

    STAGE(0, 0);
    __syncthreads();                          // drain prologue stage
    int cur = 0;
    for (int t = 0; t < 15; ++t) {
        STAGE(cur ^ 1, (t + 1) * 64);         // prefetch next K-tile (other buffer)
        COMPUTE(cur);                         // MFMA on current tile overlaps the loads
        __syncthreads();                      // one barrier/K-step
        cur ^= 1;
    }
    COMPUTE(cur);                             // last tile, nothing left to stage

    const int cm = (lane >> 4) * 4;   // C/D: col = lane&15, row = (lane>>4)*4 + reg
#pragma unroll
    for (int ni = 0; ni < 4; ++ni) {
        const int c = col0 + wn + ni * 16 + fm;
        const float bv = bias[c];
#pragma unroll
        for (int mi = 0; mi < 4; ++mi) {
#pragma unroll
            for (int r = 0; r < 4; ++r) {
                const int row = row0 + wm + mi * 16 + cm + r;
                H[(size_t)row * OUT_F + c] = f2bf(acc[mi][ni][r] + bv);
            }
        }
    }
#undef STAGE
#undef COMPUTE
}

// ---- aggregate: wave per (node, feature-quarter); 16 rows in flight ----
__global__ __launch_bounds__(256, 8) void aggregate(const unsigned short* __restrict__ H,
                                                    const int* __restrict__ ucnt,
                                                    const int* __restrict__ ucol,
                                                    float* __restrict__ out) {
    const int wave = threadIdx.x >> 6;
    const int lane = threadIdx.x & 63;
    const int bid  = blockIdx.x;
    const int q    = bid & 3;                 // feature quarter
    const int v    = (bid >> 2) * 4 + wave;   // node (bijective over 8192 blocks)
    const int n    = ucnt[v];
    const int* uq  = ucol + v * STRIDE;
    const unsigned short* Hq = H + q * 128 + lane * 2;

    float a0 = 0.f, a1 = 0.f;
    int e = 0;
    for (; e + 16 <= n; e += 16) {            // 16 rows in flight
        unsigned h[16];
#pragma unroll
        for (int t = 0; t < 16; ++t)
            h[t] = *(const unsigned*)&Hq[(size_t)uq[e + t] * OUT_F];
#pragma unroll
        for (int t = 0; t < 16; ++t) { a0 += bflo(h[t]); a1 += bfhi(h[t]); }
    }
    for (; e + 4 <= n; e += 4) {
        unsigned h[4];
#pragma unroll
        for (int t = 0; t < 4; ++t)
            h[t] = *(const unsigned*)&Hq[(size_t)uq[e + t] * OUT_F];
#pragma unroll
        for (int t = 0; t < 4; ++t) { a0 += bflo(h[t]); a1 += bfhi(h[t]); }
    }
    for (; e < n; ++e) {
        unsigned h = *(const unsigned*)&Hq[(size_t)uq[e] * OUT_F];
        a0 += bflo(h); a1 += bfhi(h);
    }
    f32x2 o = {fmaxf(a0, 0.f), fmaxf(a1, 0.f)};
    __builtin_nontemporal_store(o, (f32x2*)&out[(size_t)v * OUT_F + q * 128 + lane * 2]);
}

extern "C" void kernel_launch(void* const* d_in, const int* in_sizes, int n_in,
                              void* d_out, int out_size, void* d_ws, size_t ws_size,
                              hipStream_t stream) {
    const float* x  = (const float*)d_in[0];
    const float* W  = (const float*)d_in[1];
    const float* b  = (const float*)d_in[2];
    const int*   ei = (const int*)d_in[3];      // [2, N_EDGES]: src then dst
    float* out = (float*)d_out;

    char* ws = (char*)d_ws;
    unsigned short* H    = (unsigned short*)(ws + HID_OFF);
    unsigned short* Xb   = (unsigned short*)(ws + XB_OFF);   // Wb contiguous after
    unsigned short* Wb   = (unsigned short*)(ws + WB_OFF);
    int*            deg  = (int*)(ws + DEG_OFF);
    int*            col  = (int*)(ws + COL_OFF);
    int*            ucnt = (int*)(ws + UCNT_OFF);
    int*            ucol = (int*)(ws + UCOL_OFF);

    // 0) zero deg (stream-ordered, graph-capture legal)
    hipMemsetAsync(deg, 0, N_NODES * sizeof(int), stream);

    // 1) edge scatter (1024 blocks) overlapped with X,W bf16 conversion (4352)
    cvt_scatter<<<SCAT_BLOCKS + (NX8 + NW8) / 256, 256, 0, stream>>>(
        x, W, Xb, ei, ei + N_EDGES, deg, col);

    // 2) GEMM (256 blocks, 128x128 tile, 128 MB staged) + dedup (2048 blocks)
    gemm_dedup<<<GEMM_BLOCKS + N_NODES / 4, 256, 0, stream>>>(
        Xb, Wb, b, H, deg, col, ucol, ucnt);

    // 3) wave per (node, quarter) gather + ReLU
    aggregate<<<N_NODES * 4 / 4, 256, 0, stream>>>(H, ucnt, ucol, out);
}

// Round 11
// 144.845 us; speedup vs baseline: 1.0312x; 1.0312x over previous
//
#include <hip/hip_runtime.h>

#define N_NODES 8192
#define IN_F    1024
#define OUT_F   512
#define N_EDGES 262144
#define STRIDE  96                // fixed adjacency row stride; P(deg>=96) ~ 1e-18

// ---------------- workspace layout (bytes) ----------------
#define HID_OFF     0u            // 8192*512*2   =  8,388,608  (bf16 H)
#define XB_OFF      8388608u      // 8192*1024*2  = 16,777,216  (bf16 X)
#define WB_OFF      25165824u     // 512*1024*2   =  1,048,576  (bf16 W, contiguous after Xb)
#define DEG_OFF     26214400u     // 8192*4 = 32,768
#define COL_OFF     26247168u     // 8192*96*4 = 3,145,728 -> ends 29,392,896
#define MAX_DEG     STRIDE

typedef short  bf16x8 __attribute__((ext_vector_type(8)));
typedef float  f32x4  __attribute__((ext_vector_type(4)));
typedef float  f32x2  __attribute__((ext_vector_type(2)));

__device__ __forceinline__ unsigned short f2bf(float f) {
    unsigned u = __float_as_uint(f);
    u += 0x7fffu + ((u >> 16) & 1u);   // round-to-nearest-even
    return (unsigned short)(u >> 16);
}

__device__ __forceinline__ float bflo(unsigned u) { return __uint_as_float(u << 16); }
__device__ __forceinline__ float bfhi(unsigned u) { return __uint_as_float(u & 0xffff0000u); }

__device__ __forceinline__ void ld_lds16(const void* g, void* l) {
    __builtin_amdgcn_global_load_lds(
        (const __attribute__((address_space(1))) void*)g,
        (__attribute__((address_space(3))) void*)l, 16, 0, 0);
}

// --- fp32 -> bf16 for X and W in one launch; first 8192 threads zero deg ---
#define NX8 (N_NODES * IN_F / 8)          // 1,048,576 chunks of 8
#define NW8 (OUT_F * IN_F / 8)            //    65,536
__global__ __launch_bounds__(256) void cvt_bf16_all(const float* __restrict__ x,
                                                    const float* __restrict__ w,
                                                    unsigned short* __restrict__ xb,
                                                    int* __restrict__ deg) {
    int i = blockIdx.x * blockDim.x + threadIdx.x;
    if (i < N_NODES) deg[i] = 0;
    if (i >= NX8 + NW8) return;
    const f32x4* p = (i < NX8) ? ((const f32x4*)x + (size_t)i * 2)
                               : ((const f32x4*)w + (size_t)(i - NX8) * 2);
    f32x4 v0 = __builtin_nontemporal_load(p);      // x/w not re-read as fp32
    f32x4 v1 = __builtin_nontemporal_load(p + 1);
    uint4 o;
    o.x = (unsigned)f2bf(v0.x) | ((unsigned)f2bf(v0.y) << 16);
    o.y = (unsigned)f2bf(v0.z) | ((unsigned)f2bf(v0.w) << 16);
    o.z = (unsigned)f2bf(v1.x) | ((unsigned)f2bf(v1.y) << 16);
    o.w = (unsigned)f2bf(v1.z) | ((unsigned)f2bf(v1.w) << 16);
    *((uint4*)xb + i) = o;
}

// ------- fused: MFMA GEMM (blocks 0..255) + edge scatter (256..1279) -----
// ISOLATED CHANGE vs R4 (138.9us): tile 128x64 -> 128x128.  Staged bytes
// 196 MB -> 134 MB (R9 counters: GEMM time = staged/(7.4 TB/s), exact
// linear).  256 GEMM blocks dispatch FIRST -> each CU gets 1 GEMM block +
// 1 scatter block co-resident (64 KB LDS, 2 blk/CU); scatter's latency-bound
// atomics fill the GEMM's barrier stalls.  4 waves (2m x 2n), wave = 64x64
// out (4x4 frags, 64 acc VGPR).  Simple dbuf, 1 barrier/K-step (schedule
// edits proven neutral R1/R8).  Same XOR swizzle as always.
#define GEMM_BLOCKS 256

__global__ __launch_bounds__(256, 2) void gemm_scatter(const unsigned short* __restrict__ Xb,
                                                       const unsigned short* __restrict__ Wb,
                                                       const float* __restrict__ bias,
                                                       unsigned short* __restrict__ H,
                                                       const int* __restrict__ src,
                                                       const int* __restrict__ dst,
                                                       int* __restrict__ deg,
                                                       int* __restrict__ col) {
    __shared__ unsigned short As[2][128 * 64];   // 32 KB
    __shared__ unsigned short Bs[2][128 * 64];   // 32 KB -> 64 KB, 2 blk/CU

    const int bid = blockIdx.x;
    const int tid = threadIdx.x;

    if (bid >= GEMM_BLOCKS) {                 // ---- scatter part ----
        int e = (bid - GEMM_BLOCKS) * 256 + tid;   // 1024*256 == N_EDGES exactly
        int s = src[e];
        int slot = atomicAdd(&deg[s], 1);
        if (slot < STRIDE) col[s * STRIDE + slot] = dst[e];
        return;
    }

    // ---- GEMM part: 128x128 tile ----
    const int lane = tid & 63;
    const int wave = tid >> 6;
    const int row0 = (bid & 63) * 128;        // 64 row-tiles
    const int col0 = (bid >> 6) * 128;        // 4 col-tiles
    const int wm   = (wave & 1) * 64;
    const int wn   = (wave >> 1) * 64;
    const int fm   = lane & 15;
    const int fm7  = fm & 7;
    const int q    = lane >> 4;               // k-quad within the 32-k MFMA window

    f32x4 acc[4][4];
#pragma unroll
    for (int i = 0; i < 4; ++i)
#pragma unroll
        for (int j = 0; j < 4; ++j) acc[i][j] = (f32x4)0.f;

    // staging: slot = tid covers (r = tid>>3, swizzled k-chunk); +256 -> r+32, ...
    const int r0 = tid >> 3;                              // 0..31
    const int kp = ((tid & 7) ^ (r0 & 7)) * 8;            // swizzled k elem-offset
    const unsigned short* Xbase = Xb + (size_t)(row0 + r0) * IN_F + kp;
    const unsigned short* Wbase = Wb + (size_t)(col0 + r0) * IN_F + kp;

#define STAGE(buf, k0s) do {                                                  \
    ld_lds16(Xbase            + (k0s), &As[buf][tid * 8]);                    \
    ld_lds16(Xbase + 32*IN_F  + (k0s), &As[buf][(tid + 256) * 8]);            \
    ld_lds16(Xbase + 64*IN_F  + (k0s), &As[buf][(tid + 512) * 8]);            \
    ld_lds16(Xbase + 96*IN_F  + (k0s), &As[buf][(tid + 768) * 8]);            \
    ld_lds16(Wbase            + (k0s), &Bs[buf][tid * 8]);                    \
    ld_lds16(Wbase + 32*IN_F  + (k0s), &Bs[buf][(tid + 256) * 8]);            \
    ld_lds16(Wbase + 64*IN_F  + (k0s), &Bs[buf][(tid + 512) * 8]);            \
    ld_lds16(Wbase + 96*IN_F  + (k0s), &Bs[buf][(tid + 768) * 8]);            \
} while (0)

#define COMPUTE(buf) do {                                                     \
    _Pragma("unroll")                                                         \
    for (int s2 = 0; s2 < 2; ++s2) {                                          \
        const int kq = s2 * 4 + q;                                            \
        bf16x8 a[4], b[4];                                                    \
        _Pragma("unroll")                                                     \
        for (int mi = 0; mi < 4; ++mi)                                        \
            a[mi] = *(const bf16x8*)&As[buf][(((wm + mi*16 + fm) << 3) + (kq ^ fm7)) << 3]; \
        _Pragma("unroll")                                                     \
        for (int ni = 0; ni < 4; ++ni)                                        \
            b[ni] = *(const bf16x8*)&Bs[buf][(((wn + ni*16 + fm) << 3) + (kq ^ fm7)) << 3]; \
        _Pragma("unroll")                                                     \
        for (int mi = 0; mi < 4; ++mi)                                        \
            _Pragma("unroll")                                                 \
            for (int ni = 0; ni < 4; ++ni)                                    \
                acc[mi][ni] = __builtin_amdgcn_mfma_f32_16x16x32_bf16(        \
                    a[mi], b[ni], acc[mi][ni], 0, 0, 0);                      \
    }                                                                         \
} while (0)

    STAGE(0, 0);
    __syncthreads();                          // drain prologue stage
    int cur = 0;
    for (int t = 0; t < 15; ++t) {
        STAGE(cur ^ 1, (t + 1) * 64);         // prefetch next K-tile (other buffer)
        COMPUTE(cur);                         // MFMA on current tile overlaps the loads
        __syncthreads();                      // one barrier/K-step
        cur ^= 1;
    }
    COMPUTE(cur);                             // last tile, nothing left to stage

    const int cm = (lane >> 4) * 4;   // C/D: col = lane&15, row = (lane>>4)*4 + reg
#pragma unroll
    for (int ni = 0; ni < 4; ++ni) {
        const int c = col0 + wn + ni * 16 + fm;
        const float bv = bias[c];
#pragma unroll
        for (int mi = 0; mi < 4; ++mi) {
#pragma unroll
            for (int r = 0; r < 4; ++r) {
                const int row = row0 + wm + mi * 16 + cm + r;
                H[(size_t)row * OUT_F + c] = f2bf(acc[mi][ni][r] + bv);
            }
        }
    }
#undef STAGE
#undef COMPUTE
}

// ---- aggregate: wave per (node, feature-half). lane covers 4 feats (uint2). ----
// R4's proven version (138.9): inline dedup, 32 waves/CU, 12-deep MLP.
__global__ __launch_bounds__(256, 8) void aggregate(const unsigned short* __restrict__ H,
                                                    const int* __restrict__ dg,
                                                    const int* __restrict__ col,
                                                    float* __restrict__ out) {
    __shared__ int nbr[4][MAX_DEG];
    __shared__ int uniq[4][MAX_DEG];
    __shared__ int wcnt[4];
    const int wave = threadIdx.x >> 6;
    const int lane = threadIdx.x & 63;
    const int task = blockIdx.x * 4 + wave;
    const int v    = task >> 1;           // node
    const int half = task & 1;            // feature half (0: 0..255, 1: 256..511)
    int d = dg[v];
    if (d > MAX_DEG) d = MAX_DEG;

    if (lane == 0) wcnt[wave] = 0;
    int id0 = -1, id1 = -1;
    if (lane < d)      { id0 = col[v * STRIDE + lane];      nbr[wave][lane]      = id0; }
    if (64 + lane < d) { id1 = col[v * STRIDE + 64 + lane]; nbr[wave][64 + lane] = id1; }
    __builtin_amdgcn_wave_barrier();   // wave-synchronous; pin scheduling across LDS use

    // keep entry i iff no j<i equals it (no early exit -> LDS reads pipeline)
    bool k0 = (lane < d);
    const int lim0 = k0 ? lane : 0;
    for (int j = 0; j < lim0; ++j) k0 = k0 & (nbr[wave][j] != id0);
    bool k1 = (64 + lane < d);
    const int lim1 = k1 ? (64 + lane) : 0;
    for (int j = 0; j < lim1; ++j) k1 = k1 & (nbr[wave][j] != id1);
    if (k0) uniq[wave][atomicAdd(&wcnt[wave], 1)] = id0;
    if (k1) uniq[wave][atomicAdd(&wcnt[wave], 1)] = id1;
    __builtin_amdgcn_wave_barrier();
    const int n  = wcnt[wave];
    const int* uq = &uniq[wave][0];
    // lane covers 4 feats of this half: 64 lanes x 8 B = 512 B contiguous per row
    const unsigned short* Hh = H + half * 256 + lane * 4;

    float a0=0,a1=0,a2=0,a3=0;
    int e = 0;
    for (; e + 12 <= n; e += 12) {        // 12 rows in flight (24 VGPR of data)
        uint2 h[12];
#pragma unroll
        for (int t = 0; t < 12; ++t)
            h[t] = *(const uint2*)&Hh[(size_t)uq[e + t] * OUT_F];
#pragma unroll
        for (int t = 0; t < 12; ++t) {
            a0 += bflo(h[t].x); a1 += bfhi(h[t].x);
            a2 += bflo(h[t].y); a3 += bfhi(h[t].y);
        }
    }
    for (; e + 4 <= n; e += 4) {
        uint2 h[4];
#pragma unroll
        for (int t = 0; t < 4; ++t)
            h[t] = *(const uint2*)&Hh[(size_t)uq[e + t] * OUT_F];
#pragma unroll
        for (int t = 0; t < 4; ++t) {
            a0 += bflo(h[t].x); a1 += bfhi(h[t].x);
            a2 += bflo(h[t].y); a3 += bfhi(h[t].y);
        }
    }
    for (; e < n; ++e) {
        uint2 h0 = *(const uint2*)&Hh[(size_t)uq[e] * OUT_F];
        a0 += bflo(h0.x); a1 += bfhi(h0.x);
        a2 += bflo(h0.y); a3 += bfhi(h0.y);
    }
    f32x4 o = {fmaxf(a0,0.f), fmaxf(a1,0.f), fmaxf(a2,0.f), fmaxf(a3,0.f)};
    // out is never re-read -> nontemporal, keep L2/L3 for the H gather
    __builtin_nontemporal_store(o, (f32x4*)&out[(size_t)v * OUT_F + half * 256 + lane * 4]);
}

extern "C" void kernel_launch(void* const* d_in, const int* in_sizes, int n_in,
                              void* d_out, int out_size, void* d_ws, size_t ws_size,
                              hipStream_t stream) {
    const float* x  = (const float*)d_in[0];
    const float* W  = (const float*)d_in[1];
    const float* b  = (const float*)d_in[2];
    const int*   ei = (const int*)d_in[3];      // [2, N_EDGES]: src then dst
    float* out = (float*)d_out;

    char* ws = (char*)d_ws;
    unsigned short* H   = (unsigned short*)(ws + HID_OFF);
    unsigned short* Xb  = (unsigned short*)(ws + XB_OFF);   // Wb contiguous after
    unsigned short* Wb  = (unsigned short*)(ws + WB_OFF);
    int*            deg = (int*)(ws + DEG_OFF);
    int*            col = (int*)(ws + COL_OFF);

    // 1) convert X,W to bf16 + zero deg
    cvt_bf16_all<<<(NX8 + NW8 + 255) / 256, 256, 0, stream>>>(x, W, Xb, deg);

    // 2) GEMM (256 blocks, 128x128 tile, 134 MB staged) + edge scatter (1024 blocks)
    gemm_scatter<<<GEMM_BLOCKS + N_EDGES / 256, 256, 0, stream>>>(
        Xb, Wb, b, H, ei, ei + N_EDGES, deg, col);

    // 3) wave per (node, feature-half): 16384 tasks, inline dedup, 12-deep MLP
    aggregate<<<N_NODES * 2 / 4, 256, 0, stream>>>(H, deg, col, out);
}

// Round 12
// 140.364 us; speedup vs baseline: 1.0641x; 1.0319x over previous
//
#include <hip/hip_runtime.h>

#define N_NODES 8192
#define IN_F    1024
#define OUT_F   512
#define N_EDGES 262144
#define STRIDE  96                // fixed adjacency row stride; P(deg>=96) ~ 1e-18

// ---------------- workspace layout (bytes) ----------------
#define HID_OFF     0u            // 8192*512*2   =  8,388,608  (bf16 H)
#define XB_OFF      8388608u      // 8192*1024*2  = 16,777,216  (bf16 X)
#define WB_OFF      25165824u     // 512*1024*2   =  1,048,576  (bf16 W, contiguous after Xb)
#define DEG_OFF     26214400u     // 8192*4 = 32,768
#define COL_OFF     26247168u     // 8192*96*4 = 3,145,728 -> ends 29,392,896
#define MAX_DEG     STRIDE

typedef short  bf16x8 __attribute__((ext_vector_type(8)));
typedef float  f32x4  __attribute__((ext_vector_type(4)));

__device__ __forceinline__ unsigned short f2bf(float f) {
    unsigned u = __float_as_uint(f);
    u += 0x7fffu + ((u >> 16) & 1u);   // round-to-nearest-even
    return (unsigned short)(u >> 16);
}

__device__ __forceinline__ float bflo(unsigned u) { return __uint_as_float(u << 16); }
__device__ __forceinline__ float bfhi(unsigned u) { return __uint_as_float(u & 0xffff0000u); }

__device__ __forceinline__ void ld_lds16(const void* g, void* l) {
    __builtin_amdgcn_global_load_lds(
        (const __attribute__((address_space(1))) void*)g,
        (__attribute__((address_space(3))) void*)l, 16, 0, 0);
}

// --- fp32 -> bf16 for X and W in one launch; first 8192 threads zero deg ---
#define NX8 (N_NODES * IN_F / 8)          // 1,048,576 chunks of 8
#define NW8 (OUT_F * IN_F / 8)            //    65,536
__global__ __launch_bounds__(256) void cvt_bf16_all(const float* __restrict__ x,
                                                    const float* __restrict__ w,
                                                    unsigned short* __restrict__ xb,
                                                    int* __restrict__ deg) {
    int i = blockIdx.x * blockDim.x + threadIdx.x;
    if (i < N_NODES) deg[i] = 0;
    if (i >= NX8 + NW8) return;
    const f32x4* p = (i < NX8) ? ((const f32x4*)x + (size_t)i * 2)
                               : ((const f32x4*)w + (size_t)(i - NX8) * 2);
    f32x4 v0 = __builtin_nontemporal_load(p);      // x/w not re-read as fp32
    f32x4 v1 = __builtin_nontemporal_load(p + 1);
    uint4 o;
    o.x = (unsigned)f2bf(v0.x) | ((unsigned)f2bf(v0.y) << 16);
    o.y = (unsigned)f2bf(v0.z) | ((unsigned)f2bf(v0.w) << 16);
    o.z = (unsigned)f2bf(v1.x) | ((unsigned)f2bf(v1.y) << 16);
    o.w = (unsigned)f2bf(v1.z) | ((unsigned)f2bf(v1.w) << 16);
    *((uint4*)xb + i) = o;
}

// ------- fused: MFMA GEMM (blocks 0..511) + edge scatter (512..1535) -----
// GEMM: 128x64 tile, BK=64 (16 iters), 4 waves (2m x 2n), wave = 64x32 out.
// Measured-best config (R4: 138.9us).  The GEMM is staged-bytes/ingest-bound
// (R9: time = staged/(7.4 TB/s), linear) and the ingest rate needs >=2
// staging blocks/CU (R11: 256-block 128x128 tile regressed despite -31%
// bytes).  512 blocks x 48 KB dbuf = 2+ blocks/CU: both constraints met.
#define GEMM_BLOCKS 512

__global__ __launch_bounds__(256, 2) void gemm_scatter(const unsigned short* __restrict__ Xb,
                                                       const unsigned short* __restrict__ Wb,
                                                       const float* __restrict__ bias,
                                                       unsigned short* __restrict__ H,
                                                       const int* __restrict__ src,
                                                       const int* __restrict__ dst,
                                                       int* __restrict__ deg,
                                                       int* __restrict__ col) {
    __shared__ unsigned short As[2][128 * 64];   // 32 KB
    __shared__ unsigned short Bs[2][64 * 64];    // 16 KB

    const int bid = blockIdx.x;
    const int tid = threadIdx.x;

    if (bid >= GEMM_BLOCKS) {                 // ---- scatter part ----
        int e = (bid - GEMM_BLOCKS) * 256 + tid;   // 1024*256 == N_EDGES exactly
        int s = src[e];
        int slot = atomicAdd(&deg[s], 1);
        if (slot < STRIDE) col[s * STRIDE + slot] = dst[e];
        return;
    }

    // ---- GEMM part ----
    const int lane = tid & 63;
    const int wave = tid >> 6;
    const int row0 = (bid & 63) * 128;        // 64 row-tiles
    const int col0 = (bid >> 6) * 64;         // 8 col-tiles
    const int wm   = (wave & 1) * 64;
    const int wn   = (wave >> 1) * 32;
    const int fm   = lane & 15;
    const int fm7  = fm & 7;
    const int q    = lane >> 4;               // k-quad within the 32-k MFMA window

    f32x4 acc[4][2];
#pragma unroll
    for (int i = 0; i < 4; ++i)
#pragma unroll
        for (int j = 0; j < 2; ++j) acc[i][j] = (f32x4)0.f;

    // staging: slot = tid covers (r = tid>>3, swizzled k-chunk); +256 -> r+32, ...
    const int r0 = tid >> 3;                              // 0..31
    const int kp = ((tid & 7) ^ (r0 & 7)) * 8;            // swizzled k elem-offset
    const unsigned short* Xbase = Xb + (size_t)(row0 + r0) * IN_F + kp;
    const unsigned short* Wbase = Wb + (size_t)(col0 + r0) * IN_F + kp;

#define STAGE(buf, k0) do {                                                   \
    ld_lds16(Xbase            + (k0), &As[buf][tid * 8]);                     \
    ld_lds16(Xbase + 32*IN_F  + (k0), &As[buf][(tid + 256) * 8]);             \
    ld_lds16(Xbase + 64*IN_F  + (k0), &As[buf][(tid + 512) * 8]);             \
    ld_lds16(Xbase + 96*IN_F  + (k0), &As[buf][(tid + 768) * 8]);             \
    ld_lds16(Wbase            + (k0), &Bs[buf][tid * 8]);                     \
    ld_lds16(Wbase + 32*IN_F  + (k0), &Bs[buf][(tid + 256) * 8]);             \
} while (0)

#define COMPUTE(buf) do {                                                     \
    _Pragma("unroll")                                                         \
    for (int s = 0; s < 2; ++s) {                                             \
        const int kq = s * 4 + q;                                             \
        bf16x8 a[4], b[2];                                                    \
        _Pragma("unroll")                                                     \
        for (int mi = 0; mi < 4; ++mi)                                        \
            a[mi] = *(const bf16x8*)&As[buf][(((wm + mi*16 + fm) << 3) + (kq ^ fm7)) << 3]; \
        _Pragma("unroll")                                                     \
        for (int ni = 0; ni < 2; ++ni)                                        \
            b[ni] = *(const bf16x8*)&Bs[buf][(((wn + ni*16 + fm) << 3) + (kq ^ fm7)) << 3]; \
        _Pragma("unroll")                                                     \
        for (int mi = 0; mi < 4; ++mi)                                        \
            _Pragma("unroll")                                                 \
            for (int ni = 0; ni < 2; ++ni)                                    \
                acc[mi][ni] = __builtin_amdgcn_mfma_f32_16x16x32_bf16(        \
                    a[mi], b[ni], acc[mi][ni], 0, 0, 0);                      \
    }                                                                         \
} while (0)

    STAGE(0, 0);
    __syncthreads();                          // drain prologue stage
    int cur = 0;
    for (int t = 0; t < 15; ++t) {
        STAGE(cur ^ 1, (t + 1) * 64);         // prefetch next K-tile (other buffer)
        COMPUTE(cur);                         // MFMA on current tile overlaps the loads
        __syncthreads();                      // one barrier/K-step: drains vmcnt + sync
        cur ^= 1;
    }
    COMPUTE(cur);                             // last tile, nothing left to stage

    const int cm = (lane >> 4) * 4;   // C/D: col = lane&15, row = (lane>>4)*4 + reg
#pragma unroll
    for (int ni = 0; ni < 2; ++ni) {
        const int c = col0 + wn + ni * 16 + fm;
        const float bv = bias[c];
#pragma unroll
        for (int mi = 0; mi < 4; ++mi) {
#pragma unroll
            for (int r = 0; r < 4; ++r) {
                const int row = row0 + wm + mi * 16 + cm + r;
                H[(size_t)row * OUT_F + c] = f2bf(acc[mi][ni][r] + bv);
            }
        }
    }
#undef STAGE
#undef COMPUTE
}

// ---- aggregate: wave per (node, feature-half). lane covers 4 feats (uint2). ----
// Measured-best config (R4): inline dedup, 32 waves/CU, 12-deep MLP.  The
// gather is at the random-256B L2/L3 wall (~17 TB/s effective, R7); three
// alternative structures (16-deep/16-wave, quarter-split XCD-routed, hoisted
// dedup) all measured neutral.
__global__ __launch_bounds__(256, 8) void aggregate(const unsigned short* __restrict__ H,
                                                    const int* __restrict__ dg,
                                                    const int* __restrict__ col,
                                                    float* __restrict__ out) {
    __shared__ int nbr[4][MAX_DEG];
    __shared__ int uniq[4][MAX_DEG];
    __shared__ int wcnt[4];
    const int wave = threadIdx.x >> 6;
    const int lane = threadIdx.x & 63;
    const int task = blockIdx.x * 4 + wave;
    const int v    = task >> 1;           // node
    const int half = task & 1;            // feature half (0: 0..255, 1: 256..511)
    int d = dg[v];
    if (d > MAX_DEG) d = MAX_DEG;

    if (lane == 0) wcnt[wave] = 0;
    int id0 = -1, id1 = -1;
    if (lane < d)      { id0 = col[v * STRIDE + lane];      nbr[wave][lane]      = id0; }
    if (64 + lane < d) { id1 = col[v * STRIDE + 64 + lane]; nbr[wave][64 + lane] = id1; }
    __builtin_amdgcn_wave_barrier();   // wave-synchronous; pin scheduling across LDS use

    // keep entry i iff no j<i equals it (no early exit -> LDS reads pipeline)
    bool k0 = (lane < d);
    const int lim0 = k0 ? lane : 0;
    for (int j = 0; j < lim0; ++j) k0 = k0 & (nbr[wave][j] != id0);
    bool k1 = (64 + lane < d);
    const int lim1 = k1 ? (64 + lane) : 0;
    for (int j = 0; j < lim1; ++j) k1 = k1 & (nbr[wave][j] != id1);
    if (k0) uniq[wave][atomicAdd(&wcnt[wave], 1)] = id0;
    if (k1) uniq[wave][atomicAdd(&wcnt[wave], 1)] = id1;
    __builtin_amdgcn_wave_barrier();
    const int n  = wcnt[wave];
    const int* uq = &uniq[wave][0];
    // lane covers 4 feats of this half: 64 lanes x 8 B = 512 B contiguous per row
    const unsigned short* Hh = H + half * 256 + lane * 4;

    float a0=0,a1=0,a2=0,a3=0;
    int e = 0;
    for (; e + 12 <= n; e += 12) {        // 12 rows in flight (24 VGPR of data)
        uint2 h[12];
#pragma unroll
        for (int t = 0; t < 12; ++t)
            h[t] = *(const uint2*)&Hh[(size_t)uq[e + t] * OUT_F];
#pragma unroll
        for (int t = 0; t < 12; ++t) {
            a0 += bflo(h[t].x); a1 += bfhi(h[t].x);
            a2 += bflo(h[t].y); a3 += bfhi(h[t].y);
        }
    }
    for (; e + 4 <= n; e += 4) {
        uint2 h[4];
#pragma unroll
        for (int t = 0; t < 4; ++t)
            h[t] = *(const uint2*)&Hh[(size_t)uq[e + t] * OUT_F];
#pragma unroll
        for (int t = 0; t < 4; ++t) {
            a0 += bflo(h[t].x); a1 += bfhi(h[t].x);
            a2 += bflo(h[t].y); a3 += bfhi(h[t].y);
        }
    }
    for (; e < n; ++e) {
        uint2 h0 = *(const uint2*)&Hh[(size_t)uq[e] * OUT_F];
        a0 += bflo(h0.x); a1 += bfhi(h0.x);
        a2 += bflo(h0.y); a3 += bfhi(h0.y);
    }
    f32x4 o = {fmaxf(a0,0.f), fmaxf(a1,0.f), fmaxf(a2,0.f), fmaxf(a3,0.f)};
    // out is never re-read -> nontemporal, keep L2/L3 for the H gather
    __builtin_nontemporal_store(o, (f32x4*)&out[(size_t)v * OUT_F + half * 256 + lane * 4]);
}

extern "C" void kernel_launch(void* const* d_in, const int* in_sizes, int n_in,
                              void* d_out, int out_size, void* d_ws, size_t ws_size,
                              hipStream_t stream) {
    const float* x  = (const float*)d_in[0];
    const float* W  = (const float*)d_in[1];
    const float* b  = (const float*)d_in[2];
    const int*   ei = (const int*)d_in[3];      // [2, N_EDGES]: src then dst
    float* out = (float*)d_out;

    char* ws = (char*)d_ws;
    unsigned short* H   = (unsigned short*)(ws + HID_OFF);
    unsigned short* Xb  = (unsigned short*)(ws + XB_OFF);   // Wb contiguous after
    unsigned short* Wb  = (unsigned short*)(ws + WB_OFF);
    int*            deg = (int*)(ws + DEG_OFF);
    int*            col = (int*)(ws + COL_OFF);

    // 1) convert X,W to bf16 + zero deg
    cvt_bf16_all<<<(NX8 + NW8 + 255) / 256, 256, 0, stream>>>(x, W, Xb, deg);

    // 2) GEMM (512 blocks, 128x64 tile, dbuf) + edge scatter (1024 blocks) fused
    gemm_scatter<<<GEMM_BLOCKS + N_EDGES / 256, 256, 0, stream>>>(
        Xb, Wb, b, H, ei, ei + N_EDGES, deg, col);

    // 3) wave per (node, feature-half): 16384 tasks, inline dedup, 12-deep MLP
    aggregate<<<N_NODES * 2 / 4, 256, 0, stream>>>(H, deg, col, out);
}